// Round 3
// baseline (37607.831 us; speedup 1.0000x reference)
//
#include <hip/hip_runtime.h>

// APDL_RNN: allpass-delay LSTM. B=32, T=8192, I=1, H=256, OS_FACTOR=1.5 -> coeff=1/3.
// 128 WGs = 32 batches x 4 quartet members. Each WG owns 64 hidden units (256 gate
// rows); each thread owns ONE gate row with its 256 fp32 weights in REGISTERS as
// 16x floatx16 SSA values, PINNED via empty inline-asm "+v" operands (R2 showed the
// allocator spills/remats them otherwise: VGPR_Count stayed 148).
// 1 wave/SIMD (__launch_bounds__(256,1)) gives the 512-VGPR budget.
// Per step the quartet all-gathers the 256-dim allpass-filtered h through an
// agent-coherent buffer in d_ws with per-WG monotonic flags (parity dbuf).

#define Bn 32
#define Tn 8192
#define Hn 256

typedef float floatx16 __attribute__((ext_vector_type(16)));

static constexpr float kCoeff = 1.0f / 3.0f;  // (1-alpha)/(1+alpha), alpha=0.5

__device__ __forceinline__ float sigf(float x) {
  return __builtin_amdgcn_rcpf(1.0f + __expf(-x));
}
__device__ __forceinline__ float tanhf_fast(float x) {
  return 1.0f - 2.0f * __builtin_amdgcn_rcpf(1.0f + __expf(2.0f * x));
}
__device__ __forceinline__ float pick4(int d, float v0, float v1, float v2, float v3) {
  float r = (d == 0) ? v0 : v1;
  r = (d == 2) ? v2 : r;
  r = (d == 3) ? v3 : r;
  return r;
}

// Force V to live in VGPRs at this point; asm-defines it so loads can't be
// rematerialized into the loop.
#define PIN(V) asm volatile("" : "+v"(V))
#define PIN_ALL()                                                  \
  PIN(w0); PIN(w1); PIN(w2); PIN(w3); PIN(w4); PIN(w5); PIN(w6);   \
  PIN(w7); PIN(w8); PIN(w9); PIN(w10); PIN(w11); PIN(w12);         \
  PIN(w13); PIN(w14); PIN(w15)

// d_ws layout: int flags[32][4] (each padded to 16 ints = 64B)  -> 8192 bytes
//              float pub[32][2][256]                            -> 65536 bytes
__global__ void init_ws(int* ws) {
  int i = blockIdx.x * 256 + threadIdx.x;
  if (i < 18432) ws[i] = 0;
}

// 16 fp32 FMAs into 8 accumulators; hs reads are wave-uniform (LDS broadcast).
#define ACC16(WV, K)                                         \
  {                                                          \
    float4 p = *(const float4*)&hs[(K) + 0];                 \
    float4 q = *(const float4*)&hs[(K) + 4];                 \
    float4 r2 = *(const float4*)&hs[(K) + 8];                \
    float4 s2 = *(const float4*)&hs[(K) + 12];               \
    a0 = fmaf(WV[0], p.x, a0);   a1 = fmaf(WV[1], p.y, a1);  \
    a2 = fmaf(WV[2], p.z, a2);   a3 = fmaf(WV[3], p.w, a3);  \
    a4 = fmaf(WV[4], q.x, a4);   a5 = fmaf(WV[5], q.y, a5);  \
    a6 = fmaf(WV[6], q.z, a6);   a7 = fmaf(WV[7], q.w, a7);  \
    a0 = fmaf(WV[8], r2.x, a0);  a1 = fmaf(WV[9], r2.y, a1); \
    a2 = fmaf(WV[10], r2.z, a2); a3 = fmaf(WV[11], r2.w, a3);\
    a4 = fmaf(WV[12], s2.x, a4); a5 = fmaf(WV[13], s2.y, a5);\
    a6 = fmaf(WV[14], s2.z, a6); a7 = fmaf(WV[15], s2.w, a7);\
  }

__global__ __launch_bounds__(256, 1) void apdl_rnn(
    const float* __restrict__ x, const float* __restrict__ W_ih,
    const float* __restrict__ W_hh, const float* __restrict__ b_ih,
    const float* __restrict__ b_hh, float* __restrict__ out,
    int* __restrict__ flags, float* __restrict__ pub) {
  const int bid = blockIdx.x;
  const int w = bid >> 5;   // quartet member 0..3 (blocks b, b+32, ... -> same XCD)
  const int b = bid & 31;   // batch
  const int tid = (int)threadIdx.x;
  const int g = tid & 3;    // gate: 0=i 1=f 2=g 3=o
  const int ul = tid >> 2;  // local hidden unit 0..63
  const int u = w * 64 + ul;      // global hidden unit 0..255
  const int row = g * Hn + u;     // gate row 0..1023

  __shared__ __align__(16) float xs[Tn];  // this batch's x sequence, 32KB
  __shared__ __align__(16) float hs[Hn];  // current step's ap_h (matmul input)

  for (int i = tid; i < Tn; i += 256) xs[i] = x[b * Tn + i];

  // this thread's W_hh row: 16 x floatx16 values, pinned into VGPRs
  const float* wrow = W_hh + row * Hn;
  floatx16 w0  = *(const floatx16*)(wrow + 0 * 16);
  floatx16 w1  = *(const floatx16*)(wrow + 1 * 16);
  floatx16 w2  = *(const floatx16*)(wrow + 2 * 16);
  floatx16 w3  = *(const floatx16*)(wrow + 3 * 16);
  floatx16 w4  = *(const floatx16*)(wrow + 4 * 16);
  floatx16 w5  = *(const floatx16*)(wrow + 5 * 16);
  floatx16 w6  = *(const floatx16*)(wrow + 6 * 16);
  floatx16 w7  = *(const floatx16*)(wrow + 7 * 16);
  floatx16 w8  = *(const floatx16*)(wrow + 8 * 16);
  floatx16 w9  = *(const floatx16*)(wrow + 9 * 16);
  floatx16 w10 = *(const floatx16*)(wrow + 10 * 16);
  floatx16 w11 = *(const floatx16*)(wrow + 11 * 16);
  floatx16 w12 = *(const floatx16*)(wrow + 12 * 16);
  floatx16 w13 = *(const floatx16*)(wrow + 13 * 16);
  floatx16 w14 = *(const floatx16*)(wrow + 14 * 16);
  floatx16 w15 = *(const floatx16*)(wrow + 15 * 16);
  asm volatile("s_waitcnt vmcnt(0)" ::: "memory");  // loads complete
  PIN_ALL();                                        // now asm-defined: no remat

  const float wih = W_ih[row];
  const float bias = b_ih[row] + b_hh[row];

  int* myflags = flags + b * 4 * 16;   // [v]*16 ints
  float* mypub = pub + b * 2 * 256;    // [parity]*256 + unit

  float s1_h = 0.f, s1_c = 0.f, ap_h = 0.f, ap_c = 0.f;

  for (int t = 0; t < Tn; ++t) {
    // ---- acquire ap_h(t) for all 256 hidden units into LDS ----
    if (t == 0) {
      hs[tid] = 0.f;  // ap(0) = 0
    } else {
#pragma unroll
      for (int v = 0; v < 4; ++v) {
        while (__hip_atomic_load(myflags + v * 16, __ATOMIC_RELAXED,
                                 __HIP_MEMORY_SCOPE_AGENT) < t) { }
      }
      hs[tid] = __hip_atomic_load(mypub + (t & 1) * 256 + tid, __ATOMIC_RELAXED,
                                  __HIP_MEMORY_SCOPE_AGENT);
    }
    __syncthreads();
    PIN_ALL();  // weights must be register-resident at every iteration

    // ---- gate dot product: 256 fp32 MACs, weights in VGPRs ----
    float a0 = 0.f, a1 = 0.f, a2 = 0.f, a3 = 0.f;
    float a4 = 0.f, a5 = 0.f, a6 = 0.f, a7 = 0.f;
    ACC16(w0, 0);    ACC16(w1, 16);   ACC16(w2, 32);   ACC16(w3, 48);
    ACC16(w4, 64);   ACC16(w5, 80);   ACC16(w6, 96);   ACC16(w7, 112);
    ACC16(w8, 128);  ACC16(w9, 144);  ACC16(w10, 160); ACC16(w11, 176);
    ACC16(w12, 192); ACC16(w13, 208); ACC16(w14, 224); ACC16(w15, 240);
    float dot = ((a0 + a1) + (a2 + a3)) + ((a4 + a5) + (a6 + a7));
    float raw = dot + xs[t] * wih + bias;

    // ---- activate own gate, exchange within the 4-lane unit group ----
    float act = (g == 2) ? tanhf_fast(raw) : sigf(raw);
    float v1 = __shfl_xor(act, 1);
    float v2 = __shfl_xor(act, 2);
    float v3 = __shfl_xor(act, 3);
    float ai = pick4(g,     act, v1, v2, v3);  // sigmoid(i)
    float af = pick4(g ^ 1, act, v1, v2, v3);  // sigmoid(f)
    float ag = pick4(g ^ 2, act, v1, v2, v3);  // tanh(g)
    float ao = pick4(g ^ 3, act, v1, v2, v3);  // sigmoid(o)

    float c_new = af * ap_c + ai * ag;
    float h_new = ao * tanhf_fast(c_new);

    // ---- outputs: (y, states_h, states_c) fp32 ----
    int o = (b * Tn + t) * Hn + u;
    if (g == 0)      out[o] = h_new;                 // y
    else if (g == 2) out[67108864 + o] = h_new;      // states h
    else if (g == 1) out[134217728 + o] = c_new;     // states c

    if (t < Tn - 1) {
      // ---- allpass update: ap(t+1) = coeff*(s(t)-ap(t)) + s(t-1) ----
      float nh = kCoeff * (h_new - ap_h) + s1_h;
      float nc = kCoeff * (c_new - ap_c) + s1_c;
      s1_h = h_new; s1_c = c_new; ap_h = nh; ap_c = nc;
      if (g == 3)
        __hip_atomic_store(mypub + ((t + 1) & 1) * 256 + u, nh, __ATOMIC_RELAXED,
                           __HIP_MEMORY_SCOPE_AGENT);
      asm volatile("s_waitcnt vmcnt(0)" ::: "memory");  // drain own pub stores
      __syncthreads();                                   // all lanes drained
      if (tid == 0)
        __hip_atomic_store(myflags + w * 16, t + 1, __ATOMIC_RELAXED,
                           __HIP_MEMORY_SCOPE_AGENT);
    } else {
      if (g == 0)      out[201326592 + b * 512 + u] = ap_h;        // ap_final h
      else if (g == 1) out[201326592 + b * 512 + 256 + u] = ap_c;  // ap_final c
    }
  }
}

extern "C" void kernel_launch(void* const* d_in, const int* in_sizes, int n_in,
                              void* d_out, int out_size, void* d_ws, size_t ws_size,
                              hipStream_t stream) {
  const float* x = (const float*)d_in[0];
  const float* W_ih = (const float*)d_in[1];
  const float* W_hh = (const float*)d_in[2];
  const float* b_ih = (const float*)d_in[3];
  const float* b_hh = (const float*)d_in[4];
  float* out = (float*)d_out;
  int* flags = (int*)d_ws;
  float* pub = (float*)((char*)d_ws + 8192);

  init_ws<<<72, 256, 0, stream>>>((int*)d_ws);  // reset flags+pub every launch
  apdl_rnn<<<128, 256, 0, stream>>>(x, W_ih, W_hh, b_ih, b_hh, out, flags, pub);
}

// Round 4
// 14061.711 us; speedup vs baseline: 2.6745x; 2.6745x over previous
//
#include <hip/hip_runtime.h>

// APDL_RNN: allpass-delay LSTM. B=32, T=8192, I=1, H=256, OS_FACTOR=1.5 -> coeff=1/3.
// 128 WGs = 32 batches x 4 quartet members; 512 threads/WG (8 waves).
// Each WG owns 64 hidden units (256 gate rows). Each gate row is K-SPLIT across a
// lane pair (tid, tid^1): each thread holds 128 fp32 weights as 8 pinned floatx16
// (R3 lesson: 256 plain VGPRs is the architectural cap per wave -> 256 weights +
// working set spilled; 128 + ~60 fits).
// Cross-WG sync is flag-free: publishers store 8B (tag | valbits<<32) into a
// parity-double-buffered slot at agent scope; each reader polls its own element's
// tag. No vmcnt drains in the loop; y/h/c stores are fire-and-forget.

#define Bn 32
#define Tn 8192
#define Hn 256

typedef float floatx16 __attribute__((ext_vector_type(16)));

static constexpr float kCoeff = 1.0f / 3.0f;  // (1-alpha)/(1+alpha), alpha=0.5

__device__ __forceinline__ float sigf(float x) {
  return __builtin_amdgcn_rcpf(1.0f + __expf(-x));
}
__device__ __forceinline__ float tanhf_fast(float x) {
  return 1.0f - 2.0f * __builtin_amdgcn_rcpf(1.0f + __expf(2.0f * x));
}
__device__ __forceinline__ float pick4(int d, float v0, float v1, float v2, float v3) {
  float r = (d == 0) ? v0 : v1;
  r = (d == 2) ? v2 : r;
  r = (d == 3) ? v3 : r;
  return r;
}

// Keep weight vectors asm-defined & VGPR-resident (no remat, no spill of THEM).
#define PIN(V) asm volatile("" : "+v"(V))
#define PIN_ALL() PIN(w0); PIN(w1); PIN(w2); PIN(w3); PIN(w4); PIN(w5); PIN(w6); PIN(w7)

// d_ws: unsigned long long pub2[32][2][256]  (tag in low 32, float bits in high 32)
// = 131072 bytes. Re-zeroed every launch (tags restart at 0).
__global__ void init_ws(unsigned int* ws) {
  int i = blockIdx.x * 256 + threadIdx.x;
  if (i < 32768) ws[i] = 0;
}

// 16 fp32 MACs into 8 accumulators; hsp reads are wave-uniform-per-half (LDS broadcast).
#define ACC16(WV, K)                                         \
  {                                                          \
    float4 p = *(const float4*)&hsp[(K) + 0];                \
    float4 q = *(const float4*)&hsp[(K) + 4];                \
    float4 r2 = *(const float4*)&hsp[(K) + 8];               \
    float4 s2 = *(const float4*)&hsp[(K) + 12];              \
    a0 = fmaf(WV[0], p.x, a0);   a1 = fmaf(WV[1], p.y, a1);  \
    a2 = fmaf(WV[2], p.z, a2);   a3 = fmaf(WV[3], p.w, a3);  \
    a4 = fmaf(WV[4], q.x, a4);   a5 = fmaf(WV[5], q.y, a5);  \
    a6 = fmaf(WV[6], q.z, a6);   a7 = fmaf(WV[7], q.w, a7);  \
    a0 = fmaf(WV[8], r2.x, a0);  a1 = fmaf(WV[9], r2.y, a1); \
    a2 = fmaf(WV[10], r2.z, a2); a3 = fmaf(WV[11], r2.w, a3);\
    a4 = fmaf(WV[12], s2.x, a4); a5 = fmaf(WV[13], s2.y, a5);\
    a6 = fmaf(WV[14], s2.z, a6); a7 = fmaf(WV[15], s2.w, a7);\
  }

__global__ __launch_bounds__(512, 2) void apdl_rnn(
    const float* __restrict__ x, const float* __restrict__ W_ih,
    const float* __restrict__ W_hh, const float* __restrict__ b_ih,
    const float* __restrict__ b_hh, float* __restrict__ out,
    unsigned long long* __restrict__ pub) {
  const int bid = blockIdx.x;
  const int w = bid >> 5;    // quartet member 0..3 (bids b,b+32,b+64,b+96: same XCD heuristic)
  const int b = bid & 31;    // batch
  const int tid = (int)threadIdx.x;
  const int hf = tid & 1;    // K-half: 0 -> k in [0,128), 1 -> [128,256)
  const int p = tid >> 1;    // row-pair index 0..255
  const int g = p & 3;       // gate: 0=i 1=f 2=g 3=o
  const int ul = p >> 2;     // local hidden unit 0..63
  const int u = w * 64 + ul; // global hidden unit 0..255
  const int row = g * Hn + u;

  __shared__ __align__(16) float xs[Tn];  // this batch's x sequence, 32KB
  __shared__ __align__(16) float hs[Hn];  // current step's ap_h (GEMV input)

  for (int i = tid; i < Tn; i += 512) xs[i] = x[b * Tn + i];

  // this thread's half-row: 8 x floatx16, pinned into VGPRs (128 regs)
  const float* wrow = W_hh + row * Hn + hf * 128;
  floatx16 w0 = *(const floatx16*)(wrow + 0 * 16);
  floatx16 w1 = *(const floatx16*)(wrow + 1 * 16);
  floatx16 w2 = *(const floatx16*)(wrow + 2 * 16);
  floatx16 w3 = *(const floatx16*)(wrow + 3 * 16);
  floatx16 w4 = *(const floatx16*)(wrow + 4 * 16);
  floatx16 w5 = *(const floatx16*)(wrow + 5 * 16);
  floatx16 w6 = *(const floatx16*)(wrow + 6 * 16);
  floatx16 w7 = *(const floatx16*)(wrow + 7 * 16);
  asm volatile("s_waitcnt vmcnt(0)" ::: "memory");
  PIN_ALL();

  const float wih = W_ih[row];
  const float bias = b_ih[row] + b_hh[row];
  const float* hsp = hs + hf * 128;

  unsigned long long* mypub = pub + b * 2 * Hn;  // [parity][unit]

  float s1_h = 0.f, s1_c = 0.f, ap_h = 0.f, ap_c = 0.f;

  for (int t = 0; t < Tn; ++t) {
    // ---- acquire ap_h(t): poll own element's tag, stage to LDS ----
    if (tid < Hn) {
      if (t == 0) {
        hs[tid] = 0.f;  // ap(0) = 0
      } else {
        unsigned long long pk;
        do {
          pk = __hip_atomic_load(mypub + (t & 1) * Hn + tid, __ATOMIC_RELAXED,
                                 __HIP_MEMORY_SCOPE_AGENT);
        } while ((unsigned int)pk != (unsigned int)t);
        hs[tid] = __uint_as_float((unsigned int)(pk >> 32));
      }
    }
    __syncthreads();
    PIN_ALL();

    // ---- half-row dot: 128 fp32 MACs, weights in VGPRs ----
    float a0 = 0.f, a1 = 0.f, a2 = 0.f, a3 = 0.f;
    float a4 = 0.f, a5 = 0.f, a6 = 0.f, a7 = 0.f;
    ACC16(w0, 0);  ACC16(w1, 16); ACC16(w2, 32); ACC16(w3, 48);
    ACC16(w4, 64); ACC16(w5, 80); ACC16(w6, 96); ACC16(w7, 112);
    float half = ((a0 + a1) + (a2 + a3)) + ((a4 + a5) + (a6 + a7));
    float dot = half + __shfl_xor(half, 1);  // combine K-halves (pair lanes)
    float raw = dot + xs[t] * wih + bias;

    // ---- activate own gate, exchange across the 4 gate pairs (8 lanes/unit) ----
    float act = (g == 2) ? tanhf_fast(raw) : sigf(raw);
    float v1 = __shfl_xor(act, 2);  // gate g^1
    float v2 = __shfl_xor(act, 4);  // gate g^2
    float v3 = __shfl_xor(act, 6);  // gate g^3
    float ai = pick4(g,     act, v1, v2, v3);  // sigmoid(i)
    float af = pick4(g ^ 1, act, v1, v2, v3);  // sigmoid(f)
    float ag = pick4(g ^ 2, act, v1, v2, v3);  // tanh(g)
    float ao = pick4(g ^ 3, act, v1, v2, v3);  // sigmoid(o)

    float c_new = af * ap_c + ai * ag;
    float h_new = ao * tanhf_fast(c_new);

    if (t < Tn - 1) {
      // ---- allpass update: ap(t+1) = coeff*(s(t)-ap(t)) + s(t-1) ----
      float nh = kCoeff * (h_new - ap_h) + s1_h;
      float nc = kCoeff * (c_new - ap_c) + s1_c;
      s1_h = h_new; s1_c = c_new; ap_h = nh; ap_c = nc;
      // publish tagged value for step t+1 (one lane per unit); fire-and-forget
      if (g == 3 && hf == 0) {
        unsigned long long pk =
            ((unsigned long long)__float_as_uint(nh) << 32) | (unsigned int)(t + 1);
        __hip_atomic_store(mypub + ((t + 1) & 1) * Hn + u, pk, __ATOMIC_RELAXED,
                           __HIP_MEMORY_SCOPE_AGENT);
      }
    } else {
      if (g == 0 && hf == 0)      out[201326592 + b * 512 + u] = ap_h;        // ap_final h
      else if (g == 1 && hf == 0) out[201326592 + b * 512 + 256 + u] = ap_c;  // ap_final c
    }

    // ---- outputs: (y, states_h, states_c) fp32, fire-and-forget ----
    int o = (b * Tn + t) * Hn + u;
    if (hf == 0) {
      if (g == 0)      out[o] = h_new;             // y
      else if (g == 2) out[67108864 + o] = h_new;  // states h
      else if (g == 1) out[134217728 + o] = c_new; // states c
    }

    __syncthreads();  // hs fully consumed before next staging overwrites it
  }
}

extern "C" void kernel_launch(void* const* d_in, const int* in_sizes, int n_in,
                              void* d_out, int out_size, void* d_ws, size_t ws_size,
                              hipStream_t stream) {
  const float* x = (const float*)d_in[0];
  const float* W_ih = (const float*)d_in[1];
  const float* W_hh = (const float*)d_in[2];
  const float* b_ih = (const float*)d_in[3];
  const float* b_hh = (const float*)d_in[4];
  float* out = (float*)d_out;
  unsigned long long* pub = (unsigned long long*)d_ws;

  init_ws<<<128, 256, 0, stream>>>((unsigned int*)d_ws);  // reset tags every launch
  apdl_rnn<<<128, 512, 0, stream>>>(x, W_ih, W_hh, b_ih, b_hh, out, pub);
}

// Round 5
// 11299.437 us; speedup vs baseline: 3.3283x; 1.2445x over previous
//
#include <hip/hip_runtime.h>

// APDL_RNN: allpass-delay LSTM. B=32, T=8192, I=1, H=256, OS_FACTOR=1.5 -> coeff=1/3.
// 128 WGs = 32 batches x 4 quartet members; 512 threads/WG (8 waves).
// Each WG owns 64 hidden units (256 gate rows); each gate row K-split across a lane
// pair (tid, tid^1): 128 fp32 weights/thread as 32 pinned floatx4 (R4 lesson:
// 8x floatx16 pins -> eight 16-contiguous-VGPR constraints -> allocator parked
// weights in AGPRs (VGPR_Count=88) and shuttled per-iter; float4 granularity
// allocates trivially). Pin ONCE after load; loop-carried asm-def forbids remat.
// hs is padded (half 1 at offset 136) to kill the K vs K+128 same-bank conflict
// (R4: SQ_LDS_BANK_CONFLICT=1.07e9).
// Cross-WG sync: tagged 8B values (tag | valbits<<32), parity double-buffered,
// agent scope; readers poll their own element. No vmcnt drains in the loop.

#define Bn 32
#define Tn 8192
#define Hn 256
#define HPAD 136  // second K-half offset in padded hs (banks +8 vs +0)

typedef float floatx4 __attribute__((ext_vector_type(4)));

static constexpr float kCoeff = 1.0f / 3.0f;  // (1-alpha)/(1+alpha), alpha=0.5

__device__ __forceinline__ float sigf(float x) {
  return __builtin_amdgcn_rcpf(1.0f + __expf(-x));
}
__device__ __forceinline__ float tanhf_fast(float x) {
  return 1.0f - 2.0f * __builtin_amdgcn_rcpf(1.0f + __expf(2.0f * x));
}
__device__ __forceinline__ float pick4(int d, float v0, float v1, float v2, float v3) {
  float r = (d == 0) ? v0 : v1;
  r = (d == 2) ? v2 : r;
  r = (d == 3) ? v3 : r;
  return r;
}

// d_ws: unsigned long long pub2[32][2][256] = 131072 bytes, re-zeroed every launch.
__global__ void init_ws(unsigned int* ws) {
  int i = blockIdx.x * 256 + threadIdx.x;
  if (i < 32768) ws[i] = 0;
}

#define LOADW(i) floatx4 w##i = *(const floatx4*)(wrow + 4 * (i))
#define PINW(i) asm volatile("" : "+v"(w##i))
// 8 fp32 MACs into 8 accumulators; hsp reads are uniform-per-half (LDS broadcast).
#define ACC8(i, j, K)                                        \
  {                                                          \
    floatx4 p = *(const floatx4*)&hsp[(K)];                  \
    floatx4 q = *(const floatx4*)&hsp[(K) + 4];              \
    a0 = fmaf(w##i[0], p[0], a0); a1 = fmaf(w##i[1], p[1], a1); \
    a2 = fmaf(w##i[2], p[2], a2); a3 = fmaf(w##i[3], p[3], a3); \
    a4 = fmaf(w##j[0], q[0], a4); a5 = fmaf(w##j[1], q[1], a5); \
    a6 = fmaf(w##j[2], q[2], a6); a7 = fmaf(w##j[3], q[3], a7); \
  }

__global__ __launch_bounds__(512, 2) void apdl_rnn(
    const float* __restrict__ x, const float* __restrict__ W_ih,
    const float* __restrict__ W_hh, const float* __restrict__ b_ih,
    const float* __restrict__ b_hh, float* __restrict__ out,
    unsigned long long* __restrict__ pub) {
  const int bid = blockIdx.x;
  const int w = bid >> 5;    // quartet member 0..3
  const int b = bid & 31;    // batch
  const int tid = (int)threadIdx.x;
  const int hf = tid & 1;    // K-half
  const int p = tid >> 1;    // row-pair index 0..255
  const int g = p & 3;       // gate: 0=i 1=f 2=g 3=o
  const int ul = p >> 2;     // local hidden unit 0..63
  const int u = w * 64 + ul; // global hidden unit 0..255
  const int row = g * Hn + u;

  __shared__ __align__(16) float xs[Tn];        // this batch's x sequence, 32KB
  __shared__ __align__(16) float hs[2 * HPAD];  // padded ap_h staging

  for (int i = tid; i < Tn; i += 512) xs[i] = x[b * Tn + i];

  // this thread's half-row: 32 x floatx4, pinned once into VGPRs (128 regs)
  const float* wrow = W_hh + row * Hn + hf * 128;
  LOADW(0);  LOADW(1);  LOADW(2);  LOADW(3);  LOADW(4);  LOADW(5);  LOADW(6);  LOADW(7);
  LOADW(8);  LOADW(9);  LOADW(10); LOADW(11); LOADW(12); LOADW(13); LOADW(14); LOADW(15);
  LOADW(16); LOADW(17); LOADW(18); LOADW(19); LOADW(20); LOADW(21); LOADW(22); LOADW(23);
  LOADW(24); LOADW(25); LOADW(26); LOADW(27); LOADW(28); LOADW(29); LOADW(30); LOADW(31);
  asm volatile("s_waitcnt vmcnt(0)" ::: "memory");
  PINW(0);  PINW(1);  PINW(2);  PINW(3);  PINW(4);  PINW(5);  PINW(6);  PINW(7);
  PINW(8);  PINW(9);  PINW(10); PINW(11); PINW(12); PINW(13); PINW(14); PINW(15);
  PINW(16); PINW(17); PINW(18); PINW(19); PINW(20); PINW(21); PINW(22); PINW(23);
  PINW(24); PINW(25); PINW(26); PINW(27); PINW(28); PINW(29); PINW(30); PINW(31);

  const float wih = W_ih[row];
  const float bias = b_ih[row] + b_hh[row];
  const float* hsp = hs + hf * HPAD;

  unsigned long long* mypub = pub + b * 2 * Hn;  // [parity][unit]

  float s1_h = 0.f, s1_c = 0.f, ap_h = 0.f, ap_c = 0.f;

  for (int t = 0; t < Tn; ++t) {
    // ---- acquire ap_h(t): poll own element's tag, stage to padded LDS ----
    if (tid < Hn) {
      const int idx = tid + ((tid >> 7) << 3);  // 0..127 -> 0..127, 128..255 -> 136..263
      if (t == 0) {
        hs[idx] = 0.f;  // ap(0) = 0
      } else {
        unsigned long long pk;
        do {
          pk = __hip_atomic_load(mypub + (t & 1) * Hn + tid, __ATOMIC_RELAXED,
                                 __HIP_MEMORY_SCOPE_AGENT);
        } while ((unsigned int)pk != (unsigned int)t);
        hs[idx] = __uint_as_float((unsigned int)(pk >> 32));
      }
    }
    __syncthreads();

    // ---- half-row dot: 128 fp32 MACs, weights in VGPRs ----
    float a0 = 0.f, a1 = 0.f, a2 = 0.f, a3 = 0.f;
    float a4 = 0.f, a5 = 0.f, a6 = 0.f, a7 = 0.f;
    ACC8(0, 1, 0);     ACC8(2, 3, 8);     ACC8(4, 5, 16);    ACC8(6, 7, 24);
    ACC8(8, 9, 32);    ACC8(10, 11, 40);  ACC8(12, 13, 48);  ACC8(14, 15, 56);
    ACC8(16, 17, 64);  ACC8(18, 19, 72);  ACC8(20, 21, 80);  ACC8(22, 23, 88);
    ACC8(24, 25, 96);  ACC8(26, 27, 104); ACC8(28, 29, 112); ACC8(30, 31, 120);
    float half = ((a0 + a1) + (a2 + a3)) + ((a4 + a5) + (a6 + a7));
    float dot = half + __shfl_xor(half, 1);  // combine K-halves
    float raw = dot + xs[t] * wih + bias;

    // ---- activate own gate, exchange across the 4 gate pairs ----
    float act = (g == 2) ? tanhf_fast(raw) : sigf(raw);
    float v1 = __shfl_xor(act, 2);  // gate g^1
    float v2 = __shfl_xor(act, 4);  // gate g^2
    float v3 = __shfl_xor(act, 6);  // gate g^3
    float ai = pick4(g,     act, v1, v2, v3);  // sigmoid(i)
    float af = pick4(g ^ 1, act, v1, v2, v3);  // sigmoid(f)
    float ag = pick4(g ^ 2, act, v1, v2, v3);  // tanh(g)
    float ao = pick4(g ^ 3, act, v1, v2, v3);  // sigmoid(o)

    float c_new = af * ap_c + ai * ag;
    float h_new = ao * tanhf_fast(c_new);

    if (t < Tn - 1) {
      // ---- allpass update + publish (latency-critical, before output stores) ----
      float nh = kCoeff * (h_new - ap_h) + s1_h;
      float nc = kCoeff * (c_new - ap_c) + s1_c;
      s1_h = h_new; s1_c = c_new; ap_h = nh; ap_c = nc;
      if (g == 3 && hf == 0) {
        unsigned long long pk =
            ((unsigned long long)__float_as_uint(nh) << 32) | (unsigned int)(t + 1);
        __hip_atomic_store(mypub + ((t + 1) & 1) * Hn + u, pk, __ATOMIC_RELAXED,
                           __HIP_MEMORY_SCOPE_AGENT);
      }
    } else {
      if (g == 0 && hf == 0)      out[201326592 + b * 512 + u] = ap_h;        // ap_final h
      else if (g == 1 && hf == 0) out[201326592 + b * 512 + 256 + u] = ap_c;  // ap_final c
    }

    // ---- outputs: (y, states_h, states_c) fp32, fire-and-forget ----
    int o = (b * Tn + t) * Hn + u;
    if (hf == 0) {
      if (g == 0)      out[o] = h_new;             // y
      else if (g == 2) out[67108864 + o] = h_new;  // states h
      else if (g == 1) out[134217728 + o] = c_new; // states c
    }

    __syncthreads();  // hs fully consumed before next staging overwrites it
  }
}

extern "C" void kernel_launch(void* const* d_in, const int* in_sizes, int n_in,
                              void* d_out, int out_size, void* d_ws, size_t ws_size,
                              hipStream_t stream) {
  const float* x = (const float*)d_in[0];
  const float* W_ih = (const float*)d_in[1];
  const float* W_hh = (const float*)d_in[2];
  const float* b_ih = (const float*)d_in[3];
  const float* b_hh = (const float*)d_in[4];
  float* out = (float*)d_out;
  unsigned long long* pub = (unsigned long long*)d_ws;

  init_ws<<<128, 256, 0, stream>>>((unsigned int*)d_ws);  // reset tags every launch
  apdl_rnn<<<128, 512, 0, stream>>>(x, W_ih, W_hh, b_ih, b_hh, out, pub);
}